// Round 1
// baseline (7246.374 us; speedup 1.0000x reference)
//
#include <hip/hip_runtime.h>
#include <math.h>

// ---------------------------------------------------------------------------
// RNNv2 round 8: gate-collapse of the per-step signaling critical path.
// Theory: 3.27us/step vs ~600cy of real work; the rest was serialized hops:
//   - 8 per-chunk LDS flag gates (flag-read ~120cy + data-read ~120cy each)
//   - doneCnt release/acquire (+ waitcnt-draining release on producer side)
//   - s_sleep quanta (~130-190cy) in every spin
//   - libm tanhf on the tail
// Redesign (same global sentinel dataflow as round 7):
//   - data-as-signal in LDS: thread clears its 4 words to SENT, ONE raw
//     s_barrier/step (lgkmcnt-only wait: producer h-store never drained),
//     stagers write words as they arrive, consumers bulk ds_read_b128 all
//     chunks and sentinel-fixup -> poll read IS the data read.
//   - single barrier/step provably replaces doneCnt(t-2) parity protocol.
//   - sleepless spins with setprio(0) while waiting / setprio(1) computing.
//   - fast tanh via v_exp_f32 (guarded by __has_builtin).
// d_out = [ys (S*IN) | h_final (L*H)]
// ---------------------------------------------------------------------------

typedef unsigned int uint32;
typedef unsigned long long uint64;
typedef _Float16 half2_t __attribute__((ext_vector_type(2)));

#define S_LEN 2048
#define IN_SZ 1024
#define HID   2048
#define NLAY  4
#define NWG   256
#define BLK   512
#define H2    1024   // uints per packed h vector (HID/2)
#define SENT  0x7F7F7F7Fu

#define LD_AGENT(p)   __hip_atomic_load((p), __ATOMIC_RELAXED, __HIP_MEMORY_SCOPE_AGENT)
#define ST_AGENT(p,v) __hip_atomic_store((p), (v), __ATOMIC_RELAXED, __HIP_MEMORY_SCOPE_AGENT)

__device__ __forceinline__ float dot2(uint32 a, uint32 b, float c) {
    return __builtin_amdgcn_fdot2(__builtin_bit_cast(half2_t, a),
                                  __builtin_bit_cast(half2_t, b), c, false);
}
__device__ __forceinline__ uint32 packh2(float x, float y) {
    half2_t h; h.x = (_Float16)x; h.y = (_Float16)y;   // RNE converts
    return __builtin_bit_cast(uint32, h);
}
__device__ __forceinline__ float fast_tanh(float x) {
#if __has_builtin(__builtin_amdgcn_exp2f) && __has_builtin(__builtin_amdgcn_rcpf)
    // tanh(x) = sign(x) * (1 - 2/(exp2(2*log2e*|x|) + 1)); abs err ~1e-7
    float a = fabsf(x);
    float e = __builtin_amdgcn_exp2f(a * 2.885390081777927f);
    float r = 1.f - 2.f * __builtin_amdgcn_rcpf(e + 1.f);
    return copysignf(r, x);
#else
    return tanhf(x);
#endif
}
// re-poll any still-sentinel word of a uint4 from LDS; true if still missing
__device__ __forceinline__ bool fix4(const uint32* s, uint4& vv) {
    volatile const uint32* vs = s;
    if (vv.x == SENT) vv.x = vs[0];
    if (vv.y == SENT) vv.y = vs[1];
    if (vv.z == SENT) vv.z = vs[2];
    if (vv.w == SENT) vv.w = vs[3];
    return (vv.x == SENT) | (vv.y == SENT) | (vv.z == SENT) | (vv.w == SENT);
}

__global__ __launch_bounds__(BLK, 2) void rnn_scan(
    const float* __restrict__ Wh,   // [4][H][H]
    const float* __restrict__ Whh,  // [3][H][H]
    const float* __restrict__ xin,  // [S][H]  (x @ Wx^T, fp32)
    const float* __restrict__ Bh,   // [4][H]
    float* __restrict__ hfin,       // [4][H] (tail of d_out)
    uint32* hist)                   // [4][S][H2] packed half2, sentinel-filled
{
    __shared__ __align__(16) uint32 sh_own[2][H2];
    __shared__ __align__(16) uint32 sh_prev[2][H2];

    const int g   = blockIdx.x;
    const int l   = g >> 6;          // layer 0..3 (wave-uniform)
    const int w   = g & 63;          // wg within layer
    const int tid = threadIdx.x;
    const int v   = tid >> 6;        // wave 0..7
    const int k   = tid & 63;        // lane
    const int r0  = w * 32 + v * 4;  // first of this wave's 4 rows

    // ---- one-time: load + pack weights into registers --------------------
    // Chunk c (0..3): lane k covers cols 8k+512c..+7 = uint4 index k+64c of
    // the packed h row. wA[16*rr + 4c + q] = Wh row rr; wB likewise for Whh.
    uint32 wA[64], wB[64];
    const float4 bh4 = *(const float4*)(Bh + l * HID + r0);

    #pragma unroll
    for (int rr = 0; rr < 4; ++rr) {
        const float* wr = Wh + ((size_t)l * HID + r0 + rr) * HID;
        #pragma unroll
        for (int j = 0; j < 4; ++j) {
            const float* p = wr + 8 * k + 512 * j;
            float4 f0 = *(const float4*)p;
            float4 f1 = *(const float4*)(p + 4);
            wA[16 * rr + 4 * j + 0] = packh2(f0.x, f0.y);
            wA[16 * rr + 4 * j + 1] = packh2(f0.z, f0.w);
            wA[16 * rr + 4 * j + 2] = packh2(f1.x, f1.y);
            wA[16 * rr + 4 * j + 3] = packh2(f1.z, f1.w);
        }
    }
    if (l > 0) {
        #pragma unroll
        for (int rr = 0; rr < 4; ++rr) {
            const float* wr2 = Whh + ((size_t)(l - 1) * HID + r0 + rr) * HID;
            #pragma unroll
            for (int j = 0; j < 4; ++j) {
                const float* p = wr2 + 8 * k + 512 * j;
                float4 f0 = *(const float4*)p;
                float4 f1 = *(const float4*)(p + 4);
                wB[16 * rr + 4 * j + 0] = packh2(f0.x, f0.y);
                wB[16 * rr + 4 * j + 1] = packh2(f0.z, f0.w);
                wB[16 * rr + 4 * j + 2] = packh2(f1.x, f1.y);
                wB[16 * rr + 4 * j + 3] = packh2(f1.z, f1.w);
            }
        }
    }

    uint32* histL = hist + (size_t)l * S_LEN * H2;
    uint32* histP = hist + (size_t)(l - 1) * S_LEN * H2;  // only if l>0
    const bool needPrev = (l > 0);

    // ---- timestep loop ----------------------------------------------------
    // Thread stages own/prev words {tid, tid+512}; consumers poll the staged
    // LDS words directly (sentinel = not yet arrived).
    for (int t = 0; t < S_LEN; ++t) {
        const int  p       = t & 1;
        const bool needOwn = (t > 0);

        // layer 0: prefetch xin quad early (static data, rides across barrier)
        float4 xv = make_float4(0.f, 0.f, 0.f, 0.f);
        if (l == 0 && k == 0) xv = *(const float4*)(xin + (size_t)t * HID + r0);

        // clear this thread's words of parity buffer p (data-as-signal).
        // Safe: barrier at step t-1 ordered all waves' compute(t-2) reads of
        // buffer p before this write.
        sh_own [p][tid] = SENT; sh_own [p][tid + 512] = SENT;
        sh_prev[p][tid] = SENT; sh_prev[p][tid + 512] = SENT;

        // lgkmcnt-only barrier: clears visible WG-wide, but the producer's
        // agent h-store (vmcnt) is NOT drained -> stays fire-and-forget.
        asm volatile("s_waitcnt lgkmcnt(0)" ::: "memory");
        __builtin_amdgcn_s_barrier();

        // ---- stage: tight spin on this thread's 4 global sentinel words --
        __builtin_amdgcn_s_setprio(0);
        {
            bool dO0 = !needOwn, dO1 = !needOwn;
            bool dP0 = !needPrev, dP1 = !needPrev;
            const size_t tOwn = (size_t)(needOwn ? t - 1 : 0) * H2;
            const uint32* pO0 = histL + tOwn + tid;
            const uint32* pO1 = pO0 + 512;
            const uint32* pP0 = histP + (size_t)t * H2 + tid;
            const uint32* pP1 = pP0 + 512;
            while (!(dP0 & dP1 & dO0 & dO1)) {
                uint32 x0 = dP0 ? 0u : LD_AGENT(pP0);
                uint32 x1 = dP1 ? 0u : LD_AGENT(pP1);
                uint32 x2 = dO0 ? 0u : LD_AGENT(pO0);
                uint32 x3 = dO1 ? 0u : LD_AGENT(pO1);
                if (!dP0 && x0 != SENT) { sh_prev[p][tid]       = x0; dP0 = true; }
                if (!dP1 && x1 != SENT) { sh_prev[p][tid + 512] = x1; dP1 = true; }
                if (!dO0 && x2 != SENT) { sh_own[p][tid]        = x2; dO0 = true; }
                if (!dO1 && x3 != SENT) { sh_own[p][tid + 512]  = x3; dO1 = true; }
            }
        }
        __builtin_amdgcn_s_setprio(1);

        // ---- compute: bulk-read chunks, sentinel-fixup, dot --------------
        float acc0 = 0.f, acc1 = 0.f, acc2 = 0.f, acc3 = 0.f;

        if (needPrev) {
            uint4 gv[4];
            #pragma unroll
            for (int c = 0; c < 4; ++c)
                gv[c] = ((const uint4*)sh_prev[p])[k + 64 * c];
            for (;;) {
                bool bad = false;
                #pragma unroll
                for (int c = 0; c < 4; ++c)
                    bad |= fix4((const uint32*)sh_prev[p] + 4 * k + 256 * c, gv[c]);
                if (!bad) break;
            }
            #pragma unroll
            for (int c = 0; c < 4; ++c) {
                acc0 = dot2(wB[4 * c + 0], gv[c].x, acc0);
                acc0 = dot2(wB[4 * c + 1], gv[c].y, acc0);
                acc0 = dot2(wB[4 * c + 2], gv[c].z, acc0);
                acc0 = dot2(wB[4 * c + 3], gv[c].w, acc0);
                acc1 = dot2(wB[16 + 4 * c + 0], gv[c].x, acc1);
                acc1 = dot2(wB[16 + 4 * c + 1], gv[c].y, acc1);
                acc1 = dot2(wB[16 + 4 * c + 2], gv[c].z, acc1);
                acc1 = dot2(wB[16 + 4 * c + 3], gv[c].w, acc1);
                acc2 = dot2(wB[32 + 4 * c + 0], gv[c].x, acc2);
                acc2 = dot2(wB[32 + 4 * c + 1], gv[c].y, acc2);
                acc2 = dot2(wB[32 + 4 * c + 2], gv[c].z, acc2);
                acc2 = dot2(wB[32 + 4 * c + 3], gv[c].w, acc2);
                acc3 = dot2(wB[48 + 4 * c + 0], gv[c].x, acc3);
                acc3 = dot2(wB[48 + 4 * c + 1], gv[c].y, acc3);
                acc3 = dot2(wB[48 + 4 * c + 2], gv[c].z, acc3);
                acc3 = dot2(wB[48 + 4 * c + 3], gv[c].w, acc3);
            }
        }

        if (needOwn) {
            uint4 hv[4];
            #pragma unroll
            for (int c = 0; c < 4; ++c)
                hv[c] = ((const uint4*)sh_own[p])[k + 64 * c];
            for (;;) {
                bool bad = false;
                #pragma unroll
                for (int c = 0; c < 4; ++c)
                    bad |= fix4((const uint32*)sh_own[p] + 4 * k + 256 * c, hv[c]);
                if (!bad) break;
            }
            #pragma unroll
            for (int c = 0; c < 4; ++c) {
                acc0 = dot2(wA[4 * c + 0], hv[c].x, acc0);
                acc0 = dot2(wA[4 * c + 1], hv[c].y, acc0);
                acc0 = dot2(wA[4 * c + 2], hv[c].z, acc0);
                acc0 = dot2(wA[4 * c + 3], hv[c].w, acc0);
                acc1 = dot2(wA[16 + 4 * c + 0], hv[c].x, acc1);
                acc1 = dot2(wA[16 + 4 * c + 1], hv[c].y, acc1);
                acc1 = dot2(wA[16 + 4 * c + 2], hv[c].z, acc1);
                acc1 = dot2(wA[16 + 4 * c + 3], hv[c].w, acc1);
                acc2 = dot2(wA[32 + 4 * c + 0], hv[c].x, acc2);
                acc2 = dot2(wA[32 + 4 * c + 1], hv[c].y, acc2);
                acc2 = dot2(wA[32 + 4 * c + 2], hv[c].z, acc2);
                acc2 = dot2(wA[32 + 4 * c + 3], hv[c].w, acc2);
                acc3 = dot2(wA[48 + 4 * c + 0], hv[c].x, acc3);
                acc3 = dot2(wA[48 + 4 * c + 1], hv[c].y, acc3);
                acc3 = dot2(wA[48 + 4 * c + 2], hv[c].z, acc3);
                acc3 = dot2(wA[48 + 4 * c + 3], hv[c].w, acc3);
            }
        }

        // wave-wide butterfly reduce (4 rows)
        #pragma unroll
        for (int off = 32; off > 0; off >>= 1) {
            acc0 += __shfl_xor(acc0, off, 64);
            acc1 += __shfl_xor(acc1, off, 64);
            acc2 += __shfl_xor(acc2, off, 64);
            acc3 += __shfl_xor(acc3, off, 64);
        }

        if (k == 0) {
            float h0 = fast_tanh(acc0 + bh4.x + (l == 0 ? xv.x : 0.f));
            float h1 = fast_tanh(acc1 + bh4.y + (l == 0 ? xv.y : 0.f));
            float h2 = fast_tanh(acc2 + bh4.z + (l == 0 ? xv.z : 0.f));
            float h3 = fast_tanh(acc3 + bh4.w + (l == 0 ? xv.w : 0.f));
            // single 8B store IS the release signal (words become non-NaN)
            uint64 hw = (uint64)packh2(h0, h1) | ((uint64)packh2(h2, h3) << 32);
            ST_AGENT((uint64*)&histL[(size_t)t * H2 + (r0 >> 1)], hw);
            if (t == S_LEN - 1) {
                hfin[l * HID + r0]     = h0;
                hfin[l * HID + r0 + 1] = h1;
                hfin[l * HID + r0 + 2] = h2;
                hfin[l * HID + r0 + 3] = h3;
            }
        }
    }
}

// ---------------------------------------------------------------------------
// GEMM1: xin[t][r] = sum_k x[t][k] * Wx[r][k]   (fp32 NT-GEMM, 64x64 tile)
// ---------------------------------------------------------------------------
__global__ __launch_bounds__(256) void gemm_xin(
    const float* __restrict__ A, const float* __restrict__ B,
    float* __restrict__ C, int M, int N, int K)
{
    __shared__ float As[32][65];
    __shared__ float Bs[32][65];

    const int tid = threadIdx.x;
    const int tx = tid & 15, ty = tid >> 4;
    const int i0 = blockIdx.y * 64;
    const int j0 = blockIdx.x * 64;

    float acc[4][4] = {};

    for (int k0 = 0; k0 < K; k0 += 32) {
        #pragma unroll
        for (int ld = tid; ld < 64 * 32; ld += 256) {
            const int r = ld >> 5, kk = ld & 31;
            As[kk][r] = A[(size_t)(i0 + r) * K + k0 + kk];
            Bs[kk][r] = B[(size_t)(j0 + r) * K + k0 + kk];
        }
        __syncthreads();
        #pragma unroll
        for (int kk = 0; kk < 32; ++kk) {
            float a[4], b[4];
            #pragma unroll
            for (int u = 0; u < 4; ++u) a[u] = As[kk][ty * 4 + u];
            #pragma unroll
            for (int u = 0; u < 4; ++u) b[u] = Bs[kk][tx * 4 + u];
            #pragma unroll
            for (int u = 0; u < 4; ++u)
                #pragma unroll
                for (int q = 0; q < 4; ++q)
                    acc[u][q] += a[u] * b[q];
        }
        __syncthreads();
    }
    #pragma unroll
    for (int u = 0; u < 4; ++u)
        #pragma unroll
        for (int q = 0; q < 4; ++q)
            C[(size_t)(i0 + ty * 4 + u) * N + j0 + tx * 4 + q] = acc[u][q];
}

// ---------------------------------------------------------------------------
// Output GEMM: ys[t][j] = sum_k h3[t][k] * Wy[j][k] + By[j]
// A = hist[3] packed half2 [2048][1024u], B = Wy fp32 [1024][2048].
// ---------------------------------------------------------------------------
__global__ __launch_bounds__(256) void gemm_out(
    const uint32* __restrict__ A2, const float* __restrict__ B,
    const float* __restrict__ bias, float* __restrict__ C)
{
    __shared__ float As[32][65];
    __shared__ float Bs[32][65];

    const int tid = threadIdx.x;
    const int tx = tid & 15, ty = tid >> 4;
    const int i0 = blockIdx.y * 64;   // over M = S_LEN
    const int j0 = blockIdx.x * 64;   // over N = IN_SZ

    float acc[4][4] = {};

    for (int k0 = 0; k0 < HID; k0 += 32) {
        #pragma unroll
        for (int ld = tid; ld < 1024; ld += 256) {   // A: 64 rows x 16 uints
            const int r = ld >> 4, kk2 = ld & 15;
            half2_t h = __builtin_bit_cast(half2_t,
                A2[(size_t)(i0 + r) * H2 + (k0 >> 1) + kk2]);
            As[2 * kk2][r]     = (float)h.x;
            As[2 * kk2 + 1][r] = (float)h.y;
        }
        #pragma unroll
        for (int ld = tid; ld < 2048; ld += 256) {   // B: 64 rows x 32 k
            const int rn = ld >> 5, kk = ld & 31;
            Bs[kk][rn] = B[(size_t)(j0 + rn) * HID + k0 + kk];
        }
        __syncthreads();
        #pragma unroll
        for (int kk = 0; kk < 32; ++kk) {
            float a[4], b[4];
            #pragma unroll
            for (int u = 0; u < 4; ++u) a[u] = As[kk][ty * 4 + u];
            #pragma unroll
            for (int u = 0; u < 4; ++u) b[u] = Bs[kk][tx * 4 + u];
            #pragma unroll
            for (int u = 0; u < 4; ++u)
                #pragma unroll
                for (int q = 0; q < 4; ++q)
                    acc[u][q] += a[u] * b[q];
        }
        __syncthreads();
    }
    #pragma unroll
    for (int u = 0; u < 4; ++u)
        #pragma unroll
        for (int q = 0; q < 4; ++q) {
            const int i = i0 + ty * 4 + u;
            const int j = j0 + tx * 4 + q;
            C[(size_t)i * IN_SZ + j] = acc[u][q] + bias[j];
        }
}

// ---------------------------------------------------------------------------
extern "C" void kernel_launch(void* const* d_in, const int* in_sizes, int n_in,
                              void* d_out, int out_size, void* d_ws, size_t ws_size,
                              hipStream_t stream) {
    const float* x   = (const float*)d_in[0];
    const float* Wh  = (const float*)d_in[1];
    const float* Whh = (const float*)d_in[2];
    const float* Wx  = (const float*)d_in[3];
    const float* Wy  = (const float*)d_in[4];
    const float* Bh  = (const float*)d_in[5];
    const float* By  = (const float*)d_in[6];

    float* out  = (float*)d_out;
    float* hfin = out + (size_t)S_LEN * IN_SZ;

    // ws layout: [xin S*H fp32 = 16 MB][hist 4*S*H2 u32 = 32 MB]
    float*  xin  = (float*)d_ws;
    uint32* hist = (uint32*)d_ws + (size_t)S_LEN * HID;

    // sentinel-fill hist: 0x7F byte -> each fp16 half = NaN (never produced)
    hipMemsetAsync(hist, 0x7F, (size_t)NLAY * S_LEN * H2 * sizeof(uint32), stream);

    // xin = x @ Wx^T  (M=S, N=H, K=IN)
    gemm_xin<<<dim3(HID / 64, S_LEN / 64), 256, 0, stream>>>(
        x, Wx, xin, S_LEN, HID, IN_SZ);

    // the sequential scan (persistent, 1 WG per CU)
    rnn_scan<<<NWG, BLK, 0, stream>>>(Wh, Whh, xin, Bh, hfin, hist);

    // ys = H3 @ Wy^T + By  -> d_out
    gemm_out<<<dim3(IN_SZ / 64, S_LEN / 64), 256, 0, stream>>>(
        hist + (size_t)3 * S_LEN * H2, Wy, By, out);
}

// Round 4
// 5735.531 us; speedup vs baseline: 1.2634x; 1.2634x over previous
//
#include <hip/hip_runtime.h>
#include <math.h>

// ---------------------------------------------------------------------------
// RNNv2 round 11: back to the round-8 skeleton (verified running, 6796us),
// with two targeted, sync-structure-preserving edits:
//  (1) escalating s_sleep backoff in the global sentinel spin (2 -> 8 -> 16).
//      Probe for the L3/fabric poll-saturation theory: r7 (sleep2) == r8
//      (sleepless) within 1.5% suggests both saturate the coherence fabric
//      (~6-7 TB/s poll demand); a ~5-10x deeper throttle should clear it.
//  (2) LDS sentinel re-check via whole-tile ds_read_b128 + asm memory
//      clobber instead of volatile scalar re-reads (r8's 1.8e8 bank-conflict
//      cycles -> ~0), with s_sleep(1) backoff.
// Everything else (dataflow, barriers, ws layout 48MB, launch config) is
// byte-identical to round 8. Flag-based design (r9/r10) shelved: two
// container failures, cause unproven.
// d_out = [ys (S*IN) | h_final (L*H)]
// ---------------------------------------------------------------------------

typedef unsigned int uint32;
typedef unsigned long long uint64;
typedef _Float16 half2_t __attribute__((ext_vector_type(2)));

#define S_LEN 2048
#define IN_SZ 1024
#define HID   2048
#define NLAY  4
#define NWG   256
#define BLK   512
#define H2    1024   // uints per packed h vector (HID/2)
#define SENT  0x7F7F7F7Fu

#define LD_AGENT(p)   __hip_atomic_load((p), __ATOMIC_RELAXED, __HIP_MEMORY_SCOPE_AGENT)
#define ST_AGENT(p,v) __hip_atomic_store((p), (v), __ATOMIC_RELAXED, __HIP_MEMORY_SCOPE_AGENT)

__device__ __forceinline__ float dot2(uint32 a, uint32 b, float c) {
    return __builtin_amdgcn_fdot2(__builtin_bit_cast(half2_t, a),
                                  __builtin_bit_cast(half2_t, b), c, false);
}
__device__ __forceinline__ uint32 packh2(float x, float y) {
    half2_t h; h.x = (_Float16)x; h.y = (_Float16)y;   // RNE converts
    return __builtin_bit_cast(uint32, h);
}
__device__ __forceinline__ float fast_tanh(float x) {
#if __has_builtin(__builtin_amdgcn_exp2f) && __has_builtin(__builtin_amdgcn_rcpf)
    // tanh(x) = sign(x) * (1 - 2/(exp2(2*log2e*|x|) + 1)); abs err ~1e-6
    float a = fabsf(x);
    float e = __builtin_amdgcn_exp2f(a * 2.885390081777927f);
    float r = 1.f - 2.f * __builtin_amdgcn_rcpf(e + 1.f);
    return copysignf(r, x);
#else
    return tanhf(x);
#endif
}

__global__ __launch_bounds__(BLK, 2) void rnn_scan(
    const float* __restrict__ Wh,   // [4][H][H]
    const float* __restrict__ Whh,  // [3][H][H]
    const float* __restrict__ xin,  // [S][H]  (x @ Wx^T, fp32)
    const float* __restrict__ Bh,   // [4][H]
    float* __restrict__ hfin,       // [4][H] (tail of d_out)
    uint32* hist)                   // [4][S][H2] packed half2, sentinel-filled
{
    __shared__ __align__(16) uint32 sh_own[2][H2];
    __shared__ __align__(16) uint32 sh_prev[2][H2];

    const int g   = blockIdx.x;
    const int l   = g >> 6;          // layer 0..3 (wave-uniform)
    const int w   = g & 63;          // wg within layer
    const int tid = threadIdx.x;
    const int v   = tid >> 6;        // wave 0..7
    const int k   = tid & 63;        // lane
    const int r0  = w * 32 + v * 4;  // first of this wave's 4 rows

    // ---- one-time: load + pack weights into registers --------------------
    // Chunk c (0..3): lane k covers cols 8k+512c..+7 = uint4 index k+64c of
    // the packed h row. wA[16*rr + 4c + q] = Wh row rr; wB likewise for Whh.
    uint32 wA[64], wB[64];
    const float4 bh4 = *(const float4*)(Bh + l * HID + r0);

    #pragma unroll
    for (int rr = 0; rr < 4; ++rr) {
        const float* wr = Wh + ((size_t)l * HID + r0 + rr) * HID;
        #pragma unroll
        for (int j = 0; j < 4; ++j) {
            const float* p = wr + 8 * k + 512 * j;
            float4 f0 = *(const float4*)p;
            float4 f1 = *(const float4*)(p + 4);
            wA[16 * rr + 4 * j + 0] = packh2(f0.x, f0.y);
            wA[16 * rr + 4 * j + 1] = packh2(f0.z, f0.w);
            wA[16 * rr + 4 * j + 2] = packh2(f1.x, f1.y);
            wA[16 * rr + 4 * j + 3] = packh2(f1.z, f1.w);
        }
    }
    if (l > 0) {
        #pragma unroll
        for (int rr = 0; rr < 4; ++rr) {
            const float* wr2 = Whh + ((size_t)(l - 1) * HID + r0 + rr) * HID;
            #pragma unroll
            for (int j = 0; j < 4; ++j) {
                const float* p = wr2 + 8 * k + 512 * j;
                float4 f0 = *(const float4*)p;
                float4 f1 = *(const float4*)(p + 4);
                wB[16 * rr + 4 * j + 0] = packh2(f0.x, f0.y);
                wB[16 * rr + 4 * j + 1] = packh2(f0.z, f0.w);
                wB[16 * rr + 4 * j + 2] = packh2(f1.x, f1.y);
                wB[16 * rr + 4 * j + 3] = packh2(f1.z, f1.w);
            }
        }
    }

    uint32* histL = hist + (size_t)l * S_LEN * H2;
    uint32* histP = hist + (size_t)(l - 1) * S_LEN * H2;  // only if l>0
    const bool needPrev = (l > 0);

    // ---- timestep loop ----------------------------------------------------
    // Thread stages own/prev words {tid, tid+512}; consumers poll the staged
    // LDS words directly (sentinel = not yet arrived).
    for (int t = 0; t < S_LEN; ++t) {
        const int  p       = t & 1;
        const bool needOwn = (t > 0);

        // layer 0: prefetch xin quad early (static data, rides across barrier)
        float4 xv = make_float4(0.f, 0.f, 0.f, 0.f);
        if (l == 0 && k == 0) xv = *(const float4*)(xin + (size_t)t * HID + r0);

        // clear this thread's words of parity buffer p (data-as-signal).
        // Safe: barrier at step t-1 ordered all waves' compute(t-2) reads of
        // buffer p before this write.
        sh_own [p][tid] = SENT; sh_own [p][tid + 512] = SENT;
        sh_prev[p][tid] = SENT; sh_prev[p][tid + 512] = SENT;

        // lgkmcnt-only barrier: clears visible WG-wide, but the producer's
        // agent h-store (vmcnt) is NOT drained -> stays fire-and-forget.
        asm volatile("s_waitcnt lgkmcnt(0)" ::: "memory");
        __builtin_amdgcn_s_barrier();

        // ---- stage: spin on this thread's 4 global sentinel words --------
        // Escalating backoff: the poll-saturation probe. Miss 1 -> sleep(2)
        // (~130cy), miss 2 -> sleep(8) (~520cy), then sleep(16) (~1040cy).
        __builtin_amdgcn_s_setprio(0);
        {
            bool dO0 = !needOwn, dO1 = !needOwn;
            bool dP0 = !needPrev, dP1 = !needPrev;
            const size_t tOwn = (size_t)(needOwn ? t - 1 : 0) * H2;
            const uint32* pO0 = histL + tOwn + tid;
            const uint32* pO1 = pO0 + 512;
            const uint32* pP0 = histP + (size_t)t * H2 + tid;
            const uint32* pP1 = pP0 + 512;
            int it = 0;
            while (!(dP0 & dP1 & dO0 & dO1)) {
                uint32 x0 = dP0 ? 0u : LD_AGENT(pP0);
                uint32 x1 = dP1 ? 0u : LD_AGENT(pP1);
                uint32 x2 = dO0 ? 0u : LD_AGENT(pO0);
                uint32 x3 = dO1 ? 0u : LD_AGENT(pO1);
                if (!dP0 && x0 != SENT) { sh_prev[p][tid]       = x0; dP0 = true; }
                if (!dP1 && x1 != SENT) { sh_prev[p][tid + 512] = x1; dP1 = true; }
                if (!dO0 && x2 != SENT) { sh_own[p][tid]        = x2; dO0 = true; }
                if (!dO1 && x3 != SENT) { sh_own[p][tid + 512]  = x3; dO1 = true; }
                if (dP0 & dP1 & dO0 & dO1) break;
                if (it == 0)      __builtin_amdgcn_s_sleep(2);
                else if (it == 1) __builtin_amdgcn_s_sleep(8);
                else              __builtin_amdgcn_s_sleep(16);
                ++it;
            }
        }
        __builtin_amdgcn_s_setprio(1);

        // ---- compute: bulk vector re-read until sentinel-free, then dot --
        float acc0 = 0.f, acc1 = 0.f, acc2 = 0.f, acc3 = 0.f;

        if (needPrev) {
            uint4 gv[4];
            for (;;) {
                bool bad = false;
                #pragma unroll
                for (int c = 0; c < 4; ++c) {
                    gv[c] = ((const uint4*)sh_prev[p])[k + 64 * c];
                    bad |= (gv[c].x == SENT) | (gv[c].y == SENT) |
                           (gv[c].z == SENT) | (gv[c].w == SENT);
                }
                if (!bad) break;
                __builtin_amdgcn_s_sleep(1);
                asm volatile("" ::: "memory");   // force LDS re-read
            }
            #pragma unroll
            for (int c = 0; c < 4; ++c) {
                acc0 = dot2(wB[4 * c + 0], gv[c].x, acc0);
                acc0 = dot2(wB[4 * c + 1], gv[c].y, acc0);
                acc0 = dot2(wB[4 * c + 2], gv[c].z, acc0);
                acc0 = dot2(wB[4 * c + 3], gv[c].w, acc0);
                acc1 = dot2(wB[16 + 4 * c + 0], gv[c].x, acc1);
                acc1 = dot2(wB[16 + 4 * c + 1], gv[c].y, acc1);
                acc1 = dot2(wB[16 + 4 * c + 2], gv[c].z, acc1);
                acc1 = dot2(wB[16 + 4 * c + 3], gv[c].w, acc1);
                acc2 = dot2(wB[32 + 4 * c + 0], gv[c].x, acc2);
                acc2 = dot2(wB[32 + 4 * c + 1], gv[c].y, acc2);
                acc2 = dot2(wB[32 + 4 * c + 2], gv[c].z, acc2);
                acc2 = dot2(wB[32 + 4 * c + 3], gv[c].w, acc2);
                acc3 = dot2(wB[48 + 4 * c + 0], gv[c].x, acc3);
                acc3 = dot2(wB[48 + 4 * c + 1], gv[c].y, acc3);
                acc3 = dot2(wB[48 + 4 * c + 2], gv[c].z, acc3);
                acc3 = dot2(wB[48 + 4 * c + 3], gv[c].w, acc3);
            }
        }

        if (needOwn) {
            uint4 hv[4];
            for (;;) {
                bool bad = false;
                #pragma unroll
                for (int c = 0; c < 4; ++c) {
                    hv[c] = ((const uint4*)sh_own[p])[k + 64 * c];
                    bad |= (hv[c].x == SENT) | (hv[c].y == SENT) |
                           (hv[c].z == SENT) | (hv[c].w == SENT);
                }
                if (!bad) break;
                __builtin_amdgcn_s_sleep(1);
                asm volatile("" ::: "memory");   // force LDS re-read
            }
            #pragma unroll
            for (int c = 0; c < 4; ++c) {
                acc0 = dot2(wA[4 * c + 0], hv[c].x, acc0);
                acc0 = dot2(wA[4 * c + 1], hv[c].y, acc0);
                acc0 = dot2(wA[4 * c + 2], hv[c].z, acc0);
                acc0 = dot2(wA[4 * c + 3], hv[c].w, acc0);
                acc1 = dot2(wA[16 + 4 * c + 0], hv[c].x, acc1);
                acc1 = dot2(wA[16 + 4 * c + 1], hv[c].y, acc1);
                acc1 = dot2(wA[16 + 4 * c + 2], hv[c].z, acc1);
                acc1 = dot2(wA[16 + 4 * c + 3], hv[c].w, acc1);
                acc2 = dot2(wA[32 + 4 * c + 0], hv[c].x, acc2);
                acc2 = dot2(wA[32 + 4 * c + 1], hv[c].y, acc2);
                acc2 = dot2(wA[32 + 4 * c + 2], hv[c].z, acc2);
                acc2 = dot2(wA[32 + 4 * c + 3], hv[c].w, acc2);
                acc3 = dot2(wA[48 + 4 * c + 0], hv[c].x, acc3);
                acc3 = dot2(wA[48 + 4 * c + 1], hv[c].y, acc3);
                acc3 = dot2(wA[48 + 4 * c + 2], hv[c].z, acc3);
                acc3 = dot2(wA[48 + 4 * c + 3], hv[c].w, acc3);
            }
        }

        // wave-wide butterfly reduce (4 rows)
        #pragma unroll
        for (int off = 32; off > 0; off >>= 1) {
            acc0 += __shfl_xor(acc0, off, 64);
            acc1 += __shfl_xor(acc1, off, 64);
            acc2 += __shfl_xor(acc2, off, 64);
            acc3 += __shfl_xor(acc3, off, 64);
        }

        if (k == 0) {
            float h0 = fast_tanh(acc0 + bh4.x + (l == 0 ? xv.x : 0.f));
            float h1 = fast_tanh(acc1 + bh4.y + (l == 0 ? xv.y : 0.f));
            float h2 = fast_tanh(acc2 + bh4.z + (l == 0 ? xv.z : 0.f));
            float h3 = fast_tanh(acc3 + bh4.w + (l == 0 ? xv.w : 0.f));
            // single 8B store IS the release signal (words become non-NaN)
            uint64 hw = (uint64)packh2(h0, h1) | ((uint64)packh2(h2, h3) << 32);
            ST_AGENT((uint64*)&histL[(size_t)t * H2 + (r0 >> 1)], hw);
            if (t == S_LEN - 1) {
                hfin[l * HID + r0]     = h0;
                hfin[l * HID + r0 + 1] = h1;
                hfin[l * HID + r0 + 2] = h2;
                hfin[l * HID + r0 + 3] = h3;
            }
        }
    }
}

// ---------------------------------------------------------------------------
// GEMM1: xin[t][r] = sum_k x[t][k] * Wx[r][k]   (fp32 NT-GEMM, 64x64 tile)
// ---------------------------------------------------------------------------
__global__ __launch_bounds__(256) void gemm_xin(
    const float* __restrict__ A, const float* __restrict__ B,
    float* __restrict__ C, int M, int N, int K)
{
    __shared__ float As[32][65];
    __shared__ float Bs[32][65];

    const int tid = threadIdx.x;
    const int tx = tid & 15, ty = tid >> 4;
    const int i0 = blockIdx.y * 64;
    const int j0 = blockIdx.x * 64;

    float acc[4][4] = {};

    for (int k0 = 0; k0 < K; k0 += 32) {
        #pragma unroll
        for (int ld = tid; ld < 64 * 32; ld += 256) {
            const int r = ld >> 5, kk = ld & 31;
            As[kk][r] = A[(size_t)(i0 + r) * K + k0 + kk];
            Bs[kk][r] = B[(size_t)(j0 + r) * K + k0 + kk];
        }
        __syncthreads();
        #pragma unroll
        for (int kk = 0; kk < 32; ++kk) {
            float a[4], b[4];
            #pragma unroll
            for (int u = 0; u < 4; ++u) a[u] = As[kk][ty * 4 + u];
            #pragma unroll
            for (int u = 0; u < 4; ++u) b[u] = Bs[kk][tx * 4 + u];
            #pragma unroll
            for (int u = 0; u < 4; ++u)
                #pragma unroll
                for (int q = 0; q < 4; ++q)
                    acc[u][q] += a[u] * b[q];
        }
        __syncthreads();
    }
    #pragma unroll
    for (int u = 0; u < 4; ++u)
        #pragma unroll
        for (int q = 0; q < 4; ++q)
            C[(size_t)(i0 + ty * 4 + u) * N + j0 + tx * 4 + q] = acc[u][q];
}

// ---------------------------------------------------------------------------
// Output GEMM: ys[t][j] = sum_k h3[t][k] * Wy[j][k] + By[j]
// A = hist[3] packed half2 [2048][1024u], B = Wy fp32 [1024][2048].
// ---------------------------------------------------------------------------
__global__ __launch_bounds__(256) void gemm_out(
    const uint32* __restrict__ A2, const float* __restrict__ B,
    const float* __restrict__ bias, float* __restrict__ C)
{
    __shared__ float As[32][65];
    __shared__ float Bs[32][65];

    const int tid = threadIdx.x;
    const int tx = tid & 15, ty = tid >> 4;
    const int i0 = blockIdx.y * 64;   // over M = S_LEN
    const int j0 = blockIdx.x * 64;   // over N = IN_SZ

    float acc[4][4] = {};

    for (int k0 = 0; k0 < HID; k0 += 32) {
        #pragma unroll
        for (int ld = tid; ld < 1024; ld += 256) {   // A: 64 rows x 16 uints
            const int r = ld >> 4, kk2 = ld & 15;
            half2_t h = __builtin_bit_cast(half2_t,
                A2[(size_t)(i0 + r) * H2 + (k0 >> 1) + kk2]);
            As[2 * kk2][r]     = (float)h.x;
            As[2 * kk2 + 1][r] = (float)h.y;
        }
        #pragma unroll
        for (int ld = tid; ld < 2048; ld += 256) {   // B: 64 rows x 32 k
            const int rn = ld >> 5, kk = ld & 31;
            Bs[kk][rn] = B[(size_t)(j0 + rn) * HID + k0 + kk];
        }
        __syncthreads();
        #pragma unroll
        for (int kk = 0; kk < 32; ++kk) {
            float a[4], b[4];
            #pragma unroll
            for (int u = 0; u < 4; ++u) a[u] = As[kk][ty * 4 + u];
            #pragma unroll
            for (int u = 0; u < 4; ++u) b[u] = Bs[kk][tx * 4 + u];
            #pragma unroll
            for (int u = 0; u < 4; ++u)
                #pragma unroll
                for (int q = 0; q < 4; ++q)
                    acc[u][q] += a[u] * b[q];
        }
        __syncthreads();
    }
    #pragma unroll
    for (int u = 0; u < 4; ++u)
        #pragma unroll
        for (int q = 0; q < 4; ++q) {
            const int i = i0 + ty * 4 + u;
            const int j = j0 + tx * 4 + q;
            C[(size_t)i * IN_SZ + j] = acc[u][q] + bias[j];
        }
}

// ---------------------------------------------------------------------------
extern "C" void kernel_launch(void* const* d_in, const int* in_sizes, int n_in,
                              void* d_out, int out_size, void* d_ws, size_t ws_size,
                              hipStream_t stream) {
    const float* x   = (const float*)d_in[0];
    const float* Wh  = (const float*)d_in[1];
    const float* Whh = (const float*)d_in[2];
    const float* Wx  = (const float*)d_in[3];
    const float* Wy  = (const float*)d_in[4];
    const float* Bh  = (const float*)d_in[5];
    const float* By  = (const float*)d_in[6];

    float* out  = (float*)d_out;
    float* hfin = out + (size_t)S_LEN * IN_SZ;

    // ws layout: [xin S*H fp32 = 16 MB][hist 4*S*H2 u32 = 32 MB]
    float*  xin  = (float*)d_ws;
    uint32* hist = (uint32*)d_ws + (size_t)S_LEN * HID;

    // sentinel-fill hist: 0x7F byte -> each fp16 half = NaN (never produced)
    hipMemsetAsync(hist, 0x7F, (size_t)NLAY * S_LEN * H2 * sizeof(uint32), stream);

    // xin = x @ Wx^T  (M=S, N=H, K=IN)
    gemm_xin<<<dim3(HID / 64, S_LEN / 64), 256, 0, stream>>>(
        x, Wx, xin, S_LEN, HID, IN_SZ);

    // the sequential scan (persistent, 1 WG per CU)
    rnn_scan<<<NWG, BLK, 0, stream>>>(Wh, Whh, xin, Bh, hfin, hist);

    // ys = H3 @ Wy^T + By  -> d_out
    gemm_out<<<dim3(IN_SZ / 64, S_LEN / 64), 256, 0, stream>>>(
        hist + (size_t)3 * S_LEN * H2, Wy, By, out);
}